// Round 1
// baseline (187.266 us; speedup 1.0000x reference)
//
#include <hip/hip_runtime.h>

// One-level separable wavelet filterbank (maxflat), periodic extension.
// x: [8,3,1024,1024] f32 -> out: [4, 8,3,512,512] f32 (LL, LH, HL, HH)
//
// Fused single pass: LDS tile of input (70x70 incl. halo), row-filter to
// L/H at even cols, col-filter at even rows, write 4 subbands.

constexpr int H = 1024, W = 1024;
constexpr int NIMG = 24;            // 8*3
constexpr int HOUT = 512, WOUT = 512;
constexpr int TO = 32;              // output tile edge
constexpr int TI = 2 * TO + 6;      // 70: input tile edge incl. halo

__global__ __launch_bounds__(256)
void wfb_kernel(const float* __restrict__ x, float* __restrict__ out) {
    __shared__ float s_in[TI][TI + 2];    // 70 x 72  (pad for banks)
    __shared__ float s_L[TI][TO + 1];     // 70 x 33
    __shared__ float s_H[TI][TO + 1];

    // h (len 5, ext 2) and h1 (len 7, ext 4), exact maxflat values
    const float h0c[5] = {0.125f, 0.35355339059327373f, 1.25f,
                          0.35355339059327373f, 0.125f};
    const float h1c[7] = {0.025888347648318447f,  0.07322330470336313f,
                          -0.06878156646177083f, -0.8535533905932737f,
                          -0.06878156646177083f,  0.07322330470336313f,
                          0.025888347648318447f};

    const int tid = threadIdx.x;
    const int img = blockIdx.z;
    const int r0 = blockIdx.y * TO;   // output-row offset
    const int c0 = blockIdx.x * TO;   // output-col offset
    const float* __restrict__ xin = x + (size_t)img * H * W;

    // ---- stage input tile with periodic wrap ----
    const int rbase = 2 * r0 - 4;
    const int cbase = 2 * c0 - 4;
    for (int idx = tid; idx < TI * TI; idx += 256) {
        int r = idx / TI;
        int c = idx - r * TI;
        int gr = (rbase + r) & (H - 1);   // two's-complement & handles negatives
        int gc = (cbase + c) & (W - 1);
        s_in[r][c] = xin[gr * W + gc];
    }
    __syncthreads();

    // ---- horizontal filter at even output cols: L (5 tap) and H (7 tap) ----
    for (int idx = tid; idx < TI * TO; idx += 256) {
        int r = idx >> 5;       // tile row 0..69
        int j = idx & 31;       // output col in tile
        const float* row = &s_in[r][2 * j];
        float L  = h0c[0]*row[2] + h0c[1]*row[3] + h0c[2]*row[4]
                 + h0c[3]*row[5] + h0c[4]*row[6];
        float Hv = h1c[0]*row[0] + h1c[1]*row[1] + h1c[2]*row[2]
                 + h1c[3]*row[3] + h1c[4]*row[4] + h1c[5]*row[5]
                 + h1c[6]*row[6];
        s_L[r][j] = L;
        s_H[r][j] = Hv;
    }
    __syncthreads();

    // ---- vertical filter at even output rows; write 4 subbands ----
    constexpr size_t SB = (size_t)NIMG * HOUT * WOUT;  // per-subband stride
    float* __restrict__ o = out + (size_t)img * HOUT * WOUT;
    for (int idx = tid; idx < TO * TO; idx += 256) {
        int i = idx >> 5;
        int j = idx & 31;
        float LL = 0.f, LH = 0.f, HL = 0.f, HHv = 0.f;
        #pragma unroll
        for (int k = 0; k < 5; ++k) {
            LL += h0c[k] * s_L[2*i + 2 + k][j];
            HL += h0c[k] * s_H[2*i + 2 + k][j];
        }
        #pragma unroll
        for (int k = 0; k < 7; ++k) {
            LH  += h1c[k] * s_L[2*i + k][j];
            HHv += h1c[k] * s_H[2*i + k][j];
        }
        size_t off = (size_t)(r0 + i) * WOUT + (c0 + j);
        o[0 * SB + off] = LL;
        o[1 * SB + off] = LH;
        o[2 * SB + off] = HL;
        o[3 * SB + off] = HHv;
    }
}

extern "C" void kernel_launch(void* const* d_in, const int* in_sizes, int n_in,
                              void* d_out, int out_size, void* d_ws, size_t ws_size,
                              hipStream_t stream) {
    const float* x = (const float*)d_in[0];
    float* out = (float*)d_out;
    dim3 grid(WOUT / TO, HOUT / TO, NIMG);   // 16 x 16 x 24
    wfb_kernel<<<grid, dim3(256), 0, stream>>>(x, out);
}